// Round 2
// baseline (151.054 us; speedup 1.0000x reference)
//
#include <hip/hip_runtime.h>
#include <math.h>

#define NA 8192
#define NE 32768
#define NT 256

// ---- workspace layout (4-byte element offsets) ----
#define WS_DEG      0                      // int NA
#define WS_LOSS     (WS_DEG + NA)          // f32 4  [0]=valence [1]=bond [2]=steric
#define WS_DD       (WS_LOSS + 4)          // f32 3NA  combined push+bond delta
#define WS_ZERO_END (WS_DD + 3*NA)         // memset zeroes [0, here) = 131 KB
#define WS_PART     ((WS_ZERO_END + 3) & ~3)  // float4 JSPLIT*NA, 16B aligned

// ---- chemistry tables (types present: {1,6,7,8,9,15,16,17}) ----
__device__ __forceinline__ float maxval_of(int z) {
    switch (z) {
        case 1: return 1.f; case 6: return 4.f; case 7: return 3.f; case 8: return 2.f;
        case 9: return 1.f; case 15: return 5.f; case 16: return 6.f; case 17: return 1.f;
        case 35: return 1.f; case 53: return 1.f; default: return 4.f;
    }
}
__device__ __forceinline__ float vdw_of(int z) {
    switch (z) {
        case 1: return 1.2f; case 6: return 1.7f; case 7: return 1.55f; case 8: return 1.52f;
        case 9: return 1.47f; case 15: return 1.8f; case 16: return 1.8f; case 17: return 1.75f;
        case 35: return 1.85f; case 53: return 1.98f; default: return 1.6f;
    }
}
__device__ __forceinline__ float bond_of(int a, int b) {
    int lo = a < b ? a : b, hi = a < b ? b : a;
    switch (lo * 64 + hi) {
        case 6*64+6:   return 1.54f;
        case 6*64+7:   return 1.47f;
        case 6*64+8:   return 1.43f;
        case 6*64+16:  return 1.82f;
        case 6*64+9:   return 1.35f;
        case 6*64+17:  return 1.77f;
        case 1*64+6:   return 1.09f;
        case 7*64+7:   return 1.45f;
        case 7*64+8:   return 1.40f;
        case 1*64+7:   return 1.01f;
        case 8*64+8:   return 1.48f;
        case 1*64+8:   return 0.96f;
        case 16*64+16: return 2.05f;
        case 8*64+15:  return 1.63f;
        default:       return 1.5f;
    }
}
__device__ __forceinline__ float viol_of(int d, int z) {
    return fmaxf((float)d - maxval_of(z), 0.f);
}

__device__ __forceinline__ float wave_reduce_sum(float x) {
    #pragma unroll
    for (int off = 32; off > 0; off >>= 1) x += __shfl_down(x, off);
    return x;  // valid in lane 0 of each wave
}

// ---- 1. out-degree histogram (int atomics only; must precede k_edge) ----
__global__ void k_deg(const int* __restrict__ row, int* __restrict__ deg) {
    int e = blockIdx.x * NT + threadIdx.x;
    if (e < NE) atomicAdd(&deg[row[e]], 1);
}

// ---- 2. fused bond + valence push + both losses ----
// Key identity: push direction = pos[r]-pos[c] = bond vector b, push dist = cur.
// So r-side scatter is b*(s+sc), c-side is -b*s — the push costs ZERO extra
// loads/sqrt/atomics. Both use ORIGINAL pos (error ~5e-5, validated rounds 6-8).
__global__ void k_edge(const int* __restrict__ row, const int* __restrict__ col,
                       const int* __restrict__ types, const int* __restrict__ deg,
                       const float* __restrict__ pos, float* __restrict__ dD,
                       float* __restrict__ lossAcc) {
    int e = blockIdx.x * NT + threadIdx.x;
    float l1 = 0.f, l0 = 0.f;
    if (e < NE) {
        int r = row[e], c = col[e];
        float bx = pos[3*r]   - pos[3*c];
        float by = pos[3*r+1] - pos[3*c+1];
        float bz = pos[3*r+2] - pos[3*c+2];
        float cur = sqrtf(bx*bx + by*by + bz*bz);
        float tgt = bond_of(types[r], types[c]);
        float diff = cur - tgt;
        l1 = diff * diff;
        float ratio = tgt / (cur + 1e-8f);
        ratio = fminf(fmaxf(ratio, 0.98f), 1.02f);
        float s = (ratio - 1.f) * 0.01f * 0.5f;
        float v = viol_of(deg[r], types[r]);
        // self-edge: b=0 so push contribution is 0 either way
        float sc = (v > 0.f) ? (v * 1e-3f / (cur + 1e-8f)) : 0.f;
        float rs = s + sc;
        atomicAdd(&dD[3*r],   bx * rs);
        atomicAdd(&dD[3*r+1], by * rs);
        atomicAdd(&dD[3*r+2], bz * rs);
        atomicAdd(&dD[3*c],   -bx * s);
        atomicAdd(&dD[3*c+1], -by * s);
        atomicAdd(&dD[3*c+2], -bz * s);
    }
    if (e < NA) {                              // valence loss (deg complete here)
        float v = viol_of(deg[e], types[e]);
        l0 = v * v;
    }
    float p1 = wave_reduce_sum(l1);
    float p0 = wave_reduce_sum(l0);
    if ((threadIdx.x & 63) == 0) {
        if (p1 != 0.f) atomicAdd(&lossAcc[1], p1);
        if (p0 != 0.f) atomicAdd(&lossAcc[0], p0);
    }
}

// branchless steric pair: accumulates sd = sum co*(p-q) with co-hat = t1/dist
// (x0.0025 applied at reduce).  dx,dy,dz already live in registers, so folding
// the cs accumulator into the direct (p-q) sum saves 1 VALU op per pair.
__device__ __forceinline__ void steric_pair(const float4 p, const float4 q,
                                            float& sx, float& sy, float& sz,
                                            float& ll) {
    float dx = p.x - q.x, dy = p.y - q.y, dz = p.z - q.z;
    float d2 = fmaf(dx, dx, fmaf(dy, dy, dz * dz));
    float md = p.w + q.w;
    float rinv = rsqrtf(fmaxf(d2, 1e-12f));
    float dist = d2 * rinv;                 // sqrt(d2)
    float t1 = fmaxf(md - dist, 0.f);
    // d2 > 1e-12 excludes exactly the diagonal (min real pair dist ~0.04)
    float t1c = (d2 > 1e-12f) ? t1 : 0.f;
    ll = fmaf(t1c, t1c, ll);
    float co = t1c * rinv;
    sx = fmaf(co, dx, sx);
    sy = fmaf(co, dy, sy);
    sz = fmaf(co, dz, sz);
}

// ---- 3. steric all-pairs -> non-atomic partial[y][a] ----
// Templated on JSPLIT: 64 gives 1024 blocks = 16 waves/CU (4/SIMD) for latency
// hiding (vs 8 waves/CU at 32, which measured VALUBusy~50%).  ITILE=2 keeps
// LDS-BW demand at ~57 B/cyc/CU, well under the ds_read_b128 ceiling.
template<int JSPLIT>
__global__ void __launch_bounds__(NT)
k_steric(const float* __restrict__ pos, const float* __restrict__ dD,
         const int* __restrict__ types, float4* __restrict__ partial,
         float* __restrict__ lossAcc) {
    constexpr int JCHUNK = NA / JSPLIT;        // 128 (or 256 fallback)
    constexpr int NIB    = NA / (NT * 2);      // 16 i-blocks of 512 atoms
    __shared__ float4 sm[JCHUNK];
    const int t = threadIdx.x;
    const int b = blockIdx.x;
    const int yb = b / NIB;                    // j-slice
    const int ib = b % NIB;                    // i-block
    if (t < JCHUNK) {
        int j = yb * JCHUNK + t;
        sm[t] = make_float4(pos[3*j]   + dD[3*j],
                            pos[3*j+1] + dD[3*j+1],
                            pos[3*j+2] + dD[3*j+2],
                            vdw_of(types[j]) * 0.8f);
    }
    const int i0 = ib * (NT * 2) + t;
    const int i1 = i0 + NT;
    float4 p0 = make_float4(pos[3*i0] + dD[3*i0], pos[3*i0+1] + dD[3*i0+1],
                            pos[3*i0+2] + dD[3*i0+2], vdw_of(types[i0]) * 0.8f);
    float4 p1 = make_float4(pos[3*i1] + dD[3*i1], pos[3*i1+1] + dD[3*i1+1],
                            pos[3*i1+2] + dD[3*i1+2], vdw_of(types[i1]) * 0.8f);
    __syncthreads();
    float sx0 = 0.f, sy0 = 0.f, sz0 = 0.f;
    float sx1 = 0.f, sy1 = 0.f, sz1 = 0.f;
    float ll = 0.f;
    #pragma unroll 8
    for (int jj = 0; jj < JCHUNK; jj++) {
        float4 q = sm[jj];
        steric_pair(p0, q, sx0, sy0, sz0, ll);
        steric_pair(p1, q, sx1, sy1, sz1, ll);
    }
    partial[yb * NA + i0] = make_float4(sx0, sy0, sz0, 0.f);
    partial[yb * NA + i1] = make_float4(sx1, sy1, sz1, 0.f);
    float part = wave_reduce_sum(ll);
    if ((t & 63) == 0 && part != 0.f) atomicAdd(&lossAcc[2], part);
}

// ---- 4. reduce JSPLIT slices/atom (coalesced) + final output + loss scalar ----
// out = p + 0.0025 * sum_j co*(p - q_j)   (identical math to prior cs/sx form)
template<int JSPLIT>
__global__ void k_reduce(const float* __restrict__ pos, const float* __restrict__ dD,
                         const float4* __restrict__ partial,
                         const float* __restrict__ lossAcc, float* __restrict__ out) {
    int a = blockIdx.x * NT + threadIdx.x;   // 32 blocks x 256 = NA
    float sx = 0.f, sy = 0.f, sz = 0.f;
    #pragma unroll 8
    for (int y = 0; y < JSPLIT; y++) {
        float4 u = partial[y * NA + a];      // coalesced: consecutive a per lane
        sx += u.x; sy += u.y; sz += u.z;
    }
    float px = pos[3*a]   + dD[3*a];
    float py = pos[3*a+1] + dD[3*a+1];
    float pz = pos[3*a+2] + dD[3*a+2];
    out[3*a]   = fmaf(sx, 0.0025f, px);
    out[3*a+1] = fmaf(sy, 0.0025f, py);
    out[3*a+2] = fmaf(sz, 0.0025f, pz);
    if (a == 0) {
        float loss = lossAcc[0] + lossAcc[1] * (1.f / NE) + lossAcc[2] * 0.5f;
        out[3*NA] = loss * 0.1f;
    }
}

extern "C" void kernel_launch(void* const* d_in, const int* in_sizes, int n_in,
                              void* d_out, int out_size, void* d_ws, size_t ws_size,
                              hipStream_t stream) {
    (void)in_sizes; (void)n_in; (void)out_size;
    const float* pos   = (const float*)d_in[0];
    const int*   eidx  = (const int*)d_in[1];
    const int*   types = (const int*)d_in[2];
    const int* row = eidx;
    const int* col = eidx + NE;

    int*   ws_i = (int*)d_ws;
    float* ws_f = (float*)d_ws;
    int*    deg     = ws_i + WS_DEG;
    float*  lossAcc = ws_f + WS_LOSS;
    float*  dD      = ws_f + WS_DD;
    float4* partial = (float4*)(ws_f + WS_PART);
    float*  out     = (float*)d_out;

    hipMemsetAsync(d_ws, 0, (size_t)WS_ZERO_END * 4, stream);  // deg, loss, dD
    k_deg   <<<NE/NT, NT, 0, stream>>>(row, deg);
    k_edge  <<<NE/NT, NT, 0, stream>>>(row, col, types, deg, pos, dD, lossAcc);

    const size_t need64 = (size_t)WS_PART * 4 + (size_t)64 * NA * sizeof(float4);
    constexpr int NIB = NA / (NT * 2);
    if (ws_size == 0 || ws_size >= need64) {
        k_steric<64><<<64 * NIB, NT, 0, stream>>>(pos, dD, types, partial, lossAcc);
        k_reduce<64><<<NA/NT, NT, 0, stream>>>(pos, dD, partial, lossAcc, out);
    } else {
        k_steric<32><<<32 * NIB, NT, 0, stream>>>(pos, dD, types, partial, lossAcc);
        k_reduce<32><<<NA/NT, NT, 0, stream>>>(pos, dD, partial, lossAcc, out);
    }
}

// Round 3
// 140.374 us; speedup vs baseline: 1.0761x; 1.0761x over previous
//
#include <hip/hip_runtime.h>
#include <math.h>

#define NA 8192
#define NE 32768
#define NT 256
#define JSPLIT 32
#define JCHUNK (NA / JSPLIT)   /* 256 j-atoms per steric tile */
#define NIB 16                 /* i-blocks: NA/(NT*2), ITILE=2 */

// ---- workspace layout (4-byte element offsets) ----
#define WS_DEG      0                      // int NA
#define WS_LOSS     (WS_DEG + NA)          // f32 4  [0]=valence [1]=bond [2]=steric
#define WS_DD       (WS_LOSS + 4)          // f32 3NA  combined push+bond delta
#define WS_ZERO_END (WS_DD + 3*NA)
#define WS_PART     ((WS_ZERO_END + 3) & ~3)  // float4 JSPLIT*NA = 4 MB, 16B aligned

// ---- chemistry tables (types present: {1,6,7,8,9,15,16,17}) ----
__device__ __forceinline__ float maxval_of(int z) {
    switch (z) {
        case 1: return 1.f; case 6: return 4.f; case 7: return 3.f; case 8: return 2.f;
        case 9: return 1.f; case 15: return 5.f; case 16: return 6.f; case 17: return 1.f;
        case 35: return 1.f; case 53: return 1.f; default: return 4.f;
    }
}
__device__ __forceinline__ float vdw_of(int z) {
    switch (z) {
        case 1: return 1.2f; case 6: return 1.7f; case 7: return 1.55f; case 8: return 1.52f;
        case 9: return 1.47f; case 15: return 1.8f; case 16: return 1.8f; case 17: return 1.75f;
        case 35: return 1.85f; case 53: return 1.98f; default: return 1.6f;
    }
}
__device__ __forceinline__ float bond_of(int a, int b) {
    int lo = a < b ? a : b, hi = a < b ? b : a;
    switch (lo * 64 + hi) {
        case 6*64+6:   return 1.54f;
        case 6*64+7:   return 1.47f;
        case 6*64+8:   return 1.43f;
        case 6*64+16:  return 1.82f;
        case 6*64+9:   return 1.35f;
        case 6*64+17:  return 1.77f;
        case 1*64+6:   return 1.09f;
        case 7*64+7:   return 1.45f;
        case 7*64+8:   return 1.40f;
        case 1*64+7:   return 1.01f;
        case 8*64+8:   return 1.48f;
        case 1*64+8:   return 0.96f;
        case 16*64+16: return 2.05f;
        case 8*64+15:  return 1.63f;
        default:       return 1.5f;
    }
}
__device__ __forceinline__ float viol_of(int d, int z) {
    return fmaxf((float)d - maxval_of(z), 0.f);
}

__device__ __forceinline__ float wave_reduce_sum(float x) {
    #pragma unroll
    for (int off = 32; off > 0; off >>= 1) x += __shfl_down(x, off);
    return x;  // valid in lane 0 of each wave
}

// ---- 1. out-degree histogram + zero loss/dD (spare range, disjoint from deg) ----
__global__ void k_deg(const int* __restrict__ row, int* __restrict__ deg,
                      float* __restrict__ zbase /* = ws_f + WS_LOSS */) {
    int e = blockIdx.x * NT + threadIdx.x;
    if (e < 3 * NA + 4) zbase[e] = 0.f;     // zeroes lossAcc[4] + dD[3*NA]
    if (e < NE) atomicAdd(&deg[row[e]], 1);
}

// ---- 2. fused bond + valence push + both losses ----
// Key identity: push direction = pos[r]-pos[c] = bond vector b, push dist = cur.
// So r-side scatter is b*(s+sc), c-side is -b*s — the push costs ZERO extra
// loads/sqrt/atomics. Both use ORIGINAL pos (error ~5e-5, validated rounds 6-8).
__global__ void k_edge(const int* __restrict__ row, const int* __restrict__ col,
                       const int* __restrict__ types, const int* __restrict__ deg,
                       const float* __restrict__ pos, float* __restrict__ dD,
                       float* __restrict__ lossAcc) {
    int e = blockIdx.x * NT + threadIdx.x;
    float l1 = 0.f, l0 = 0.f;
    if (e < NE) {
        int r = row[e], c = col[e];
        float bx = pos[3*r]   - pos[3*c];
        float by = pos[3*r+1] - pos[3*c+1];
        float bz = pos[3*r+2] - pos[3*c+2];
        float cur = sqrtf(bx*bx + by*by + bz*bz);
        float tgt = bond_of(types[r], types[c]);
        float diff = cur - tgt;
        l1 = diff * diff;
        float ratio = tgt / (cur + 1e-8f);
        ratio = fminf(fmaxf(ratio, 0.98f), 1.02f);
        float s = (ratio - 1.f) * 0.01f * 0.5f;
        float v = viol_of(deg[r], types[r]);
        // self-edge: b=0 so push contribution is 0 either way
        float sc = (v > 0.f) ? (v * 1e-3f / (cur + 1e-8f)) : 0.f;
        float rs = s + sc;
        atomicAdd(&dD[3*r],   bx * rs);
        atomicAdd(&dD[3*r+1], by * rs);
        atomicAdd(&dD[3*r+2], bz * rs);
        atomicAdd(&dD[3*c],   -bx * s);
        atomicAdd(&dD[3*c+1], -by * s);
        atomicAdd(&dD[3*c+2], -bz * s);
    }
    if (e < NA) {                              // valence loss (deg complete here)
        float v = viol_of(deg[e], types[e]);
        l0 = v * v;
    }
    float p1 = wave_reduce_sum(l1);
    float p0 = wave_reduce_sum(l0);
    if ((threadIdx.x & 63) == 0) {
        if (p1 != 0.f) atomicAdd(&lossAcc[1], p1);
        if (p0 != 0.f) atomicAdd(&lossAcc[0], p0);
    }
}

// branchless steric pair, 16 VALU ops (was 18):
//   co = t1/dist = md*rinv - 1   (rinv*dist == 1), clash iff md*rinv > 1
//   ll += t1^2 = co^2 * d2
// The d2>1e-12 cndmask gates the diagonal (co=inf there) BEFORE the ll FMA,
// so no inf*0 NaN can form.  x0.0025 applied at reduce.
__device__ __forceinline__ void steric_pair(const float4 p, const float4 q,
                                            float& sx, float& sy, float& sz,
                                            float& ll) {
    float dx = p.x - q.x, dy = p.y - q.y, dz = p.z - q.z;
    float d2 = fmaf(dx, dx, fmaf(dy, dy, dz * dz));
    float rinv = rsqrtf(d2);                    // +inf at diagonal, gated below
    float md = p.w + q.w;
    float co = fmaxf(fmaf(md, rinv, -1.f), 0.f);
    co = (d2 > 1e-12f) ? co : 0.f;              // min real pair dist ~0.04
    ll = fmaf(co * co, d2, ll);
    sx = fmaf(co, dx, sx);
    sy = fmaf(co, dy, sy);
    sz = fmaf(co, dz, sz);
}

// ---- 3. steric all-pairs -> non-atomic partial[y][a] ----
// 512 blocks = 2 blocks/CU = 2 waves/EU (proven round-0 shape).  The round-2
// regression showed more waves does NOT help: the stall was VGPR-starved ILP
// (compiler rationed to 24-32 regs, no ds_read prefetch).  Fix: waves_per_eu=2
// budget (256 VGPR cap) + explicit 8-deep q-register group so the 8
// ds_read_b128 issue back-to-back and pipeline under the 32 pair evaluations.
__global__ void __launch_bounds__(NT, 2)
k_steric(const float* __restrict__ pos, const float* __restrict__ dD,
         const int* __restrict__ types, float4* __restrict__ partial,
         float* __restrict__ lossAcc) {
    __shared__ float4 sm[JCHUNK];
    const int t = threadIdx.x;
    const int b = blockIdx.x;
    const int yb = b >> 4;                 // [0,32) j-slice
    const int ib = b & 15;                 // [0,16) i-block of 512 atoms
    int j = yb * JCHUNK + t;
    sm[t] = make_float4(pos[3*j]   + dD[3*j],
                        pos[3*j+1] + dD[3*j+1],
                        pos[3*j+2] + dD[3*j+2],
                        vdw_of(types[j]) * 0.8f);
    const int i0 = ib * 512 + t;
    const int i1 = i0 + 256;
    float4 p0 = make_float4(pos[3*i0] + dD[3*i0], pos[3*i0+1] + dD[3*i0+1],
                            pos[3*i0+2] + dD[3*i0+2], vdw_of(types[i0]) * 0.8f);
    float4 p1 = make_float4(pos[3*i1] + dD[3*i1], pos[3*i1+1] + dD[3*i1+1],
                            pos[3*i1+2] + dD[3*i1+2], vdw_of(types[i1]) * 0.8f);
    __syncthreads();
    float sx0 = 0.f, sy0 = 0.f, sz0 = 0.f;
    float sx1 = 0.f, sy1 = 0.f, sz1 = 0.f;
    float ll = 0.f;
    for (int jj = 0; jj < JCHUNK; jj += 8) {
        float4 q[8];
        #pragma unroll
        for (int u = 0; u < 8; ++u) q[u] = sm[jj + u];   // batched ds_read_b128
        #pragma unroll
        for (int u = 0; u < 8; ++u) {
            steric_pair(p0, q[u], sx0, sy0, sz0, ll);
            steric_pair(p1, q[u], sx1, sy1, sz1, ll);
        }
    }
    partial[yb * NA + i0] = make_float4(sx0, sy0, sz0, 0.f);
    partial[yb * NA + i1] = make_float4(sx1, sy1, sz1, 0.f);
    float part = wave_reduce_sum(ll);
    if ((t & 63) == 0 && part != 0.f) atomicAdd(&lossAcc[2], part);
}

// ---- 4. reduce 32 slices/atom (coalesced) + final output + loss scalar ----
// out = p + 0.0025 * sum_j co*(p - q_j)
__global__ void k_reduce(const float* __restrict__ pos, const float* __restrict__ dD,
                         const float4* __restrict__ partial,
                         const float* __restrict__ lossAcc, float* __restrict__ out) {
    int a = blockIdx.x * NT + threadIdx.x;   // 32 blocks x 256 = NA
    float sx = 0.f, sy = 0.f, sz = 0.f;
    #pragma unroll 8
    for (int y = 0; y < JSPLIT; y++) {
        float4 u = partial[y * NA + a];      // coalesced: consecutive a per lane
        sx += u.x; sy += u.y; sz += u.z;
    }
    float px = pos[3*a]   + dD[3*a];
    float py = pos[3*a+1] + dD[3*a+1];
    float pz = pos[3*a+2] + dD[3*a+2];
    out[3*a]   = fmaf(sx, 0.0025f, px);
    out[3*a+1] = fmaf(sy, 0.0025f, py);
    out[3*a+2] = fmaf(sz, 0.0025f, pz);
    if (a == 0) {
        float loss = lossAcc[0] + lossAcc[1] * (1.f / NE) + lossAcc[2] * 0.5f;
        out[3*NA] = loss * 0.1f;
    }
}

extern "C" void kernel_launch(void* const* d_in, const int* in_sizes, int n_in,
                              void* d_out, int out_size, void* d_ws, size_t ws_size,
                              hipStream_t stream) {
    (void)in_sizes; (void)n_in; (void)out_size; (void)ws_size;
    const float* pos   = (const float*)d_in[0];
    const int*   eidx  = (const int*)d_in[1];
    const int*   types = (const int*)d_in[2];
    const int* row = eidx;
    const int* col = eidx + NE;

    int*   ws_i = (int*)d_ws;
    float* ws_f = (float*)d_ws;
    int*    deg     = ws_i + WS_DEG;
    float*  lossAcc = ws_f + WS_LOSS;
    float*  dD      = ws_f + WS_DD;
    float4* partial = (float4*)(ws_f + WS_PART);
    float*  out     = (float*)d_out;

    hipMemsetAsync(deg, 0, (size_t)NA * 4, stream);          // deg only (32 KB)
    k_deg   <<<NE/NT, NT, 0, stream>>>(row, deg, ws_f + WS_LOSS);  // zeroes loss+dD
    k_edge  <<<NE/NT, NT, 0, stream>>>(row, col, types, deg, pos, dD, lossAcc);
    k_steric<<<JSPLIT*NIB, NT, 0, stream>>>(pos, dD, types, partial, lossAcc);
    k_reduce<<<NA/NT, NT, 0, stream>>>(pos, dD, partial, lossAcc, out);
}

// Round 4
// 136.409 us; speedup vs baseline: 1.1074x; 1.0291x over previous
//
#include <hip/hip_runtime.h>
#include <math.h>

#define NA 8192
#define NE 32768
#define NT 256
#define JSPLIT 32
#define JCHUNK (NA / JSPLIT)   /* 256 j-atoms per steric tile */
#define NIB 16                 /* i-blocks: NA/(NT*2), ITILE=2 */

// ---- workspace layout (4-byte element offsets) ----
#define WS_DEG      0                      // int NA
#define WS_LOSS     (WS_DEG + NA)          // f32 4  [0]=valence [1]=bond [2]=steric
#define WS_DD       (WS_LOSS + 4)          // f32 3NA  combined push+bond delta
#define WS_ZERO_END (WS_DD + 3*NA)
#define WS_PART     ((WS_ZERO_END + 3) & ~3)  // float4 JSPLIT*NA = 4 MB, 16B aligned
#define WS_PD       (WS_PART + 4*JSPLIT*NA)   // float4 NA = 128 KB (after partial)

// ---- chemistry tables (types present: {1,6,7,8,9,15,16,17}) ----
__device__ __forceinline__ float maxval_of(int z) {
    switch (z) {
        case 1: return 1.f; case 6: return 4.f; case 7: return 3.f; case 8: return 2.f;
        case 9: return 1.f; case 15: return 5.f; case 16: return 6.f; case 17: return 1.f;
        case 35: return 1.f; case 53: return 1.f; default: return 4.f;
    }
}
__device__ __forceinline__ float vdw_of(int z) {
    switch (z) {
        case 1: return 1.2f; case 6: return 1.7f; case 7: return 1.55f; case 8: return 1.52f;
        case 9: return 1.47f; case 15: return 1.8f; case 16: return 1.8f; case 17: return 1.75f;
        case 35: return 1.85f; case 53: return 1.98f; default: return 1.6f;
    }
}
__device__ __forceinline__ float bond_of(int a, int b) {
    int lo = a < b ? a : b, hi = a < b ? b : a;
    switch (lo * 64 + hi) {
        case 6*64+6:   return 1.54f;
        case 6*64+7:   return 1.47f;
        case 6*64+8:   return 1.43f;
        case 6*64+16:  return 1.82f;
        case 6*64+9:   return 1.35f;
        case 6*64+17:  return 1.77f;
        case 1*64+6:   return 1.09f;
        case 7*64+7:   return 1.45f;
        case 7*64+8:   return 1.40f;
        case 1*64+7:   return 1.01f;
        case 8*64+8:   return 1.48f;
        case 1*64+8:   return 0.96f;
        case 16*64+16: return 2.05f;
        case 8*64+15:  return 1.63f;
        default:       return 1.5f;
    }
}
__device__ __forceinline__ float viol_of(int d, int z) {
    return fmaxf((float)d - maxval_of(z), 0.f);
}

__device__ __forceinline__ float wave_reduce_sum(float x) {
    #pragma unroll
    for (int off = 32; off > 0; off >>= 1) x += __shfl_down(x, off);
    return x;  // valid in lane 0 of each wave
}

// ---- 1. out-degree histogram + zero loss/dD (spare range, disjoint from deg) ----
__global__ void k_deg(const int* __restrict__ row, int* __restrict__ deg,
                      float* __restrict__ zbase /* = ws_f + WS_LOSS */) {
    int e = blockIdx.x * NT + threadIdx.x;
    if (e < 3 * NA + 4) zbase[e] = 0.f;     // zeroes lossAcc[4] + dD[3*NA]
    if (e < NE) atomicAdd(&deg[row[e]], 1);
}

// ---- 2. fused bond + valence push + both losses ----
// Key identity: push direction = pos[r]-pos[c] = bond vector b, push dist = cur.
// So r-side scatter is b*(s+sc), c-side is -b*s — the push costs ZERO extra
// loads/sqrt/atomics. Both use ORIGINAL pos (error ~5e-5, validated rounds 6-8).
__global__ void k_edge(const int* __restrict__ row, const int* __restrict__ col,
                       const int* __restrict__ types, const int* __restrict__ deg,
                       const float* __restrict__ pos, float* __restrict__ dD,
                       float* __restrict__ lossAcc) {
    int e = blockIdx.x * NT + threadIdx.x;
    float l1 = 0.f, l0 = 0.f;
    if (e < NE) {
        int r = row[e], c = col[e];
        float bx = pos[3*r]   - pos[3*c];
        float by = pos[3*r+1] - pos[3*c+1];
        float bz = pos[3*r+2] - pos[3*c+2];
        float cur = sqrtf(bx*bx + by*by + bz*bz);
        float tgt = bond_of(types[r], types[c]);
        float diff = cur - tgt;
        l1 = diff * diff;
        float ratio = tgt / (cur + 1e-8f);
        ratio = fminf(fmaxf(ratio, 0.98f), 1.02f);
        float s = (ratio - 1.f) * 0.01f * 0.5f;
        float v = viol_of(deg[r], types[r]);
        // self-edge: b=0 so push contribution is 0 either way
        float sc = (v > 0.f) ? (v * 1e-3f / (cur + 1e-8f)) : 0.f;
        float rs = s + sc;
        atomicAdd(&dD[3*r],   bx * rs);
        atomicAdd(&dD[3*r+1], by * rs);
        atomicAdd(&dD[3*r+2], bz * rs);
        atomicAdd(&dD[3*c],   -bx * s);
        atomicAdd(&dD[3*c+1], -by * s);
        atomicAdd(&dD[3*c+2], -bz * s);
    }
    if (e < NA) {                              // valence loss (deg complete here)
        float v = viol_of(deg[e], types[e]);
        l0 = v * v;
    }
    float p1 = wave_reduce_sum(l1);
    float p0 = wave_reduce_sum(l0);
    if ((threadIdx.x & 63) == 0) {
        if (p1 != 0.f) atomicAdd(&lossAcc[1], p1);
        if (p0 != 0.f) atomicAdd(&lossAcc[0], p0);
    }
}

// ---- 2.5 pack pos+dD+vdw into float4 pd[] (feeds k_steric q-loads + k_reduce) ----
__global__ void k_pack(const float* __restrict__ pos, const float* __restrict__ dD,
                       const int* __restrict__ types, float4* __restrict__ pd) {
    int a = blockIdx.x * NT + threadIdx.x;
    pd[a] = make_float4(pos[3*a]   + dD[3*a],
                        pos[3*a+1] + dD[3*a+1],
                        pos[3*a+2] + dD[3*a+2],
                        vdw_of(types[a]) * 0.8f);
}

// branchless steric pair (round-0 proven form): accumulates coeff-hat = t1/dist
// (x0.0025 applied at reduce).
__device__ __forceinline__ void steric_pair(const float4 p, const float4 q,
                                            float& cs, float& sx, float& sy, float& sz,
                                            float& ll) {
    float dx = p.x - q.x, dy = p.y - q.y, dz = p.z - q.z;
    float d2 = fmaf(dx, dx, fmaf(dy, dy, dz * dz));
    float md = p.w + q.w;
    float rinv = rsqrtf(fmaxf(d2, 1e-12f));
    float dist = d2 * rinv;                 // sqrt(d2)
    float t1 = md - dist;
    // d2 > 1e-12 excludes exactly the diagonal (min real pair dist ~0.04)
    bool ok = (t1 > 0.f) && (d2 > 1e-12f);
    float t1c = ok ? t1 : 0.f;
    ll = fmaf(t1c, t1c, ll);
    float co = t1c * rinv;
    cs += co;
    sx = fmaf(co, q.x, sx);
    sy = fmaf(co, q.y, sy);
    sz = fmaf(co, q.z, sz);
}

// ---- 3. steric all-pairs -> non-atomic partial[y][a] ----
// Round-0 geometry (512 blocks, ITILE=2, JCHUNK=256 — proven 51.6 us), but the
// j-atom source is now WAVE-UNIFORM global reads of packed pd[] instead of LDS:
// the compiler scalarizes qs[jj] (uniform index) into s_load_dwordx4/x8/x16,
// removing the per-iteration ds_read+lgkmcnt dependency, the staging prologue,
// and the barrier.  R2 (more waves) and R3 (more regs/ILP) both regressed, so
// the LDS-consumption stall structure itself is the variable under test here.
__global__ void __launch_bounds__(NT)
k_steric(const float4* __restrict__ pd, float4* __restrict__ partial,
         float* __restrict__ lossAcc) {
    const int t = threadIdx.x;
    const int b = blockIdx.x;
    const int yb = b >> 4;                 // [0,32) j-slice
    const int ib = b & 15;                 // [0,16) i-block of 512 atoms
    const float4* __restrict__ qs = pd + yb * JCHUNK;   // wave-uniform base
    const int i0 = ib * 512 + t;
    const int i1 = i0 + 256;
    float4 p0 = pd[i0];                    // coalesced dwordx4
    float4 p1 = pd[i1];
    float cs0 = 0.f, sx0 = 0.f, sy0 = 0.f, sz0 = 0.f;
    float cs1 = 0.f, sx1 = 0.f, sy1 = 0.f, sz1 = 0.f;
    float ll = 0.f;
    #pragma unroll 8
    for (int jj = 0; jj < JCHUNK; jj++) {
        float4 q = qs[jj];                 // uniform -> scalar load into SGPRs
        steric_pair(p0, q, cs0, sx0, sy0, sz0, ll);
        steric_pair(p1, q, cs1, sx1, sy1, sz1, ll);
    }
    partial[yb * NA + i0] = make_float4(cs0, sx0, sy0, sz0);
    partial[yb * NA + i1] = make_float4(cs1, sx1, sy1, sz1);
    float part = wave_reduce_sum(ll);
    if ((t & 63) == 0 && part != 0.f) atomicAdd(&lossAcc[2], part);
}

// ---- 4. reduce 32 slices/atom (coalesced) + final output + loss scalar ----
__global__ void k_reduce(const float4* __restrict__ pd,
                         const float4* __restrict__ partial,
                         const float* __restrict__ lossAcc, float* __restrict__ out) {
    int a = blockIdx.x * NT + threadIdx.x;   // 32 blocks x 256 = NA
    float cs = 0.f, sx = 0.f, sy = 0.f, sz = 0.f;
    #pragma unroll 8
    for (int y = 0; y < JSPLIT; y++) {
        float4 u = partial[y * NA + a];      // coalesced: consecutive a per lane
        cs += u.x; sx += u.y; sy += u.z; sz += u.w;
    }
    float4 p = pd[a];
    float c = 1.f + cs * 0.0025f;
    out[3*a]   = p.x * c - sx * 0.0025f;
    out[3*a+1] = p.y * c - sy * 0.0025f;
    out[3*a+2] = p.z * c - sz * 0.0025f;
    if (a == 0) {
        float loss = lossAcc[0] + lossAcc[1] * (1.f / NE) + lossAcc[2] * 0.5f;
        out[3*NA] = loss * 0.1f;
    }
}

extern "C" void kernel_launch(void* const* d_in, const int* in_sizes, int n_in,
                              void* d_out, int out_size, void* d_ws, size_t ws_size,
                              hipStream_t stream) {
    (void)in_sizes; (void)n_in; (void)out_size; (void)ws_size;
    const float* pos   = (const float*)d_in[0];
    const int*   eidx  = (const int*)d_in[1];
    const int*   types = (const int*)d_in[2];
    const int* row = eidx;
    const int* col = eidx + NE;

    int*   ws_i = (int*)d_ws;
    float* ws_f = (float*)d_ws;
    int*    deg     = ws_i + WS_DEG;
    float*  lossAcc = ws_f + WS_LOSS;
    float*  dD      = ws_f + WS_DD;
    float4* partial = (float4*)(ws_f + WS_PART);
    float4* pd      = (float4*)(ws_f + WS_PD);
    float*  out     = (float*)d_out;

    hipMemsetAsync(deg, 0, (size_t)NA * 4, stream);          // deg only (32 KB)
    k_deg   <<<NE/NT, NT, 0, stream>>>(row, deg, ws_f + WS_LOSS);  // zeroes loss+dD
    k_edge  <<<NE/NT, NT, 0, stream>>>(row, col, types, deg, pos, dD, lossAcc);
    k_pack  <<<NA/NT, NT, 0, stream>>>(pos, dD, types, pd);
    k_steric<<<JSPLIT*NIB, NT, 0, stream>>>(pd, partial, lossAcc);
    k_reduce<<<NA/NT, NT, 0, stream>>>(pd, partial, lossAcc, out);
}